// Round 4
// baseline (502.764 us; speedup 1.0000x reference)
//
#include <hip/hip_runtime.h>

#define NN 50000
#define NE 800000
#define D  64
#define TILE 64
#define TPB 512
#define NBLK 196   // ceil(NN/256)

// ---------------- CSR build ----------------

__global__ __launch_bounds__(256) void k_count(const int* __restrict__ ei, int* __restrict__ deg) {
    int e = blockIdx.x * 256 + threadIdx.x;
    if (e < NE) atomicAdd(&deg[ei[NE + e]], 1);
}

__global__ __launch_bounds__(256) void k_bsum(const int* __restrict__ deg, int* __restrict__ bsum) {
    __shared__ int s[256];
    int t = threadIdx.x;
    int i = blockIdx.x * 256 + t;
    s[t] = (i < NN) ? deg[i] : 0;
    __syncthreads();
    for (int off = 128; off > 0; off >>= 1) {
        if (t < off) s[t] += s[t + off];
        __syncthreads();
    }
    if (t == 0) bsum[blockIdx.x] = s[0];
}

__global__ __launch_bounds__(256) void k_boff(const int* __restrict__ bsum,
                                              int* __restrict__ boff,
                                              int* __restrict__ row_ptr) {
    __shared__ int s[256];
    int t = threadIdx.x;
    int v = (t < NBLK) ? bsum[t] : 0;
    s[t] = v;
    __syncthreads();
    for (int off = 1; off < 256; off <<= 1) {
        int u = (t >= off) ? s[t - off] : 0;
        __syncthreads();
        s[t] += u;
        __syncthreads();
    }
    boff[t] = s[t] - v;
    if (t == 0) row_ptr[NN] = NE;
}

__global__ __launch_bounds__(256) void k_scan2(const int* __restrict__ deg,
                                               const int* __restrict__ boff,
                                               int* __restrict__ row_ptr,
                                               int* __restrict__ cursor) {
    __shared__ int s[256];
    int t = threadIdx.x;
    int i = blockIdx.x * 256 + t;
    int v = (i < NN) ? deg[i] : 0;
    s[t] = v;
    __syncthreads();
    for (int off = 1; off < 256; off <<= 1) {
        int u = (t >= off) ? s[t - off] : 0;
        __syncthreads();
        s[t] += u;
        __syncthreads();
    }
    int excl = s[t] - v + boff[blockIdx.x];
    if (i < NN) { row_ptr[i] = excl; cursor[i] = excl; }
}

__global__ __launch_bounds__(256) void k_fill(const int* __restrict__ ei,
                                              int* __restrict__ cursor,
                                              int* __restrict__ colv) {
    int e = blockIdx.x * 256 + threadIdx.x;
    if (e < NE) {
        int d = ei[NE + e];
        int p = atomicAdd(&cursor[d], 1);
        colv[p] = ei[e];
    }
}

// ---------------- shared device helpers ----------------

__device__ __forceinline__ void load_w(float (&sW)[D][D], const float* __restrict__ W, int tid) {
    const float4* w4 = (const float4*)W;
    float4* s4 = (float4*)sW;
    for (int i = tid; i < D * D / 4; i += TPB) s4[i] = w4[i];
}

__device__ __forceinline__ void acc_init(float acc[2][4], const float* sB, int tc) {
    #pragma unroll
    for (int c = 0; c < 4; ++c) { acc[0][c] = sB[tc * 4 + c]; acc[1][c] = sB[tc * 4 + c]; }
}

__device__ __forceinline__ void layer_acc(float acc[2][4], const float* zr0, const float* zr1,
                                          const float (&sW)[D][D], int tc) {
    #pragma unroll 16
    for (int k = 0; k < D; ++k) {
        float z0 = zr0[k], z1 = zr1[k];
        #pragma unroll
        for (int c = 0; c < 4; ++c) {
            float w = sW[k][tc * 4 + c];
            acc[0][c] += z0 * w;
            acc[1][c] += z1 * w;
        }
    }
}

__device__ __forceinline__ void relu_wb(float acc[2][4], float* zr0, float* zr1, int tc) {
    float4 h0, h1;
    h0.x = fmaxf(acc[0][0], 0.f); h0.y = fmaxf(acc[0][1], 0.f);
    h0.z = fmaxf(acc[0][2], 0.f); h0.w = fmaxf(acc[0][3], 0.f);
    h1.x = fmaxf(acc[1][0], 0.f); h1.y = fmaxf(acc[1][1], 0.f);
    h1.z = fmaxf(acc[1][2], 0.f); h1.w = fmaxf(acc[1][3], 0.f);
    *(float4*)&zr0[tc * 4] = h0;
    *(float4*)&zr1[tc * 4] = h1;
}

__device__ __forceinline__ void store_rows(float acc[2][4], float4* __restrict__ out4,
                                           int node0, int tr, int tc) {
    #pragma unroll
    for (int i = 0; i < 2; ++i) {
        int n = node0 + tr * 2 + i;
        if (n < NN) {
            float4 o;
            o.x = acc[i][0]; o.y = acc[i][1]; o.z = acc[i][2]; o.w = acc[i][3];
            out4[n * 16 + tc] = o;
        }
    }
}

// gather: one wave per dst row; 4 groups of 16 lanes; stride 4, unroll 4.
__device__ __forceinline__ float4 gather_row(const float4* __restrict__ h4,
                                             const int* __restrict__ row_ptr,
                                             const int* __restrict__ colv,
                                             int n, int g, int q) {
    float4 a0 = make_float4(0.f, 0.f, 0.f, 0.f);
    float4 a1 = make_float4(0.f, 0.f, 0.f, 0.f);
    float4 a2 = make_float4(0.f, 0.f, 0.f, 0.f);
    float4 a3 = make_float4(0.f, 0.f, 0.f, 0.f);
    if (n >= 0) {
        if (g == 0) a0 = h4[n * 16 + q];           // self term
        int e1 = row_ptr[n + 1];
        int e  = row_ptr[n] + g;
        for (; e + 12 < e1; e += 16) {
            int s0 = colv[e], s1 = colv[e + 4], s2 = colv[e + 8], s3 = colv[e + 12];
            float4 v0 = h4[s0 * 16 + q];
            float4 v1 = h4[s1 * 16 + q];
            float4 v2 = h4[s2 * 16 + q];
            float4 v3 = h4[s3 * 16 + q];
            a0.x += v0.x; a0.y += v0.y; a0.z += v0.z; a0.w += v0.w;
            a1.x += v1.x; a1.y += v1.y; a1.z += v1.z; a1.w += v1.w;
            a2.x += v2.x; a2.y += v2.y; a2.z += v2.z; a2.w += v2.w;
            a3.x += v3.x; a3.y += v3.y; a3.z += v3.z; a3.w += v3.w;
        }
        for (; e < e1; e += 4) {
            float4 v = h4[colv[e] * 16 + q];
            a1.x += v.x; a1.y += v.y; a1.z += v.z; a1.w += v.w;
        }
        a0.x += a1.x + a2.x + a3.x;
        a0.y += a1.y + a2.y + a3.y;
        a0.z += a1.z + a2.z + a3.z;
        a0.w += a1.w + a2.w + a3.w;
    }
    a0.x += __shfl_xor(a0.x, 16); a0.y += __shfl_xor(a0.y, 16);
    a0.z += __shfl_xor(a0.z, 16); a0.w += __shfl_xor(a0.w, 16);
    a0.x += __shfl_xor(a0.x, 32); a0.y += __shfl_xor(a0.y, 32);
    a0.z += __shfl_xor(a0.z, 32); a0.w += __shfl_xor(a0.w, 32);
    return a0;
}

// ---------------- one gather of x, three MLPs (params 0/1/2) ----------------

__global__ __launch_bounds__(TPB) void k_aggmlp3(
    const float4* __restrict__ h4,
    const int* __restrict__ row_ptr,
    const int* __restrict__ colv,
    const float* __restrict__ W1a, const float* __restrict__ b1a,
    const float* __restrict__ W2a, const float* __restrict__ b2a,
    const float* __restrict__ W1b, const float* __restrict__ b1b,
    const float* __restrict__ W2b, const float* __restrict__ b2b,
    const float* __restrict__ W1c, const float* __restrict__ b1c,
    const float* __restrict__ W2c, const float* __restrict__ b2c,
    float4* __restrict__ outA, float4* __restrict__ outB, float4* __restrict__ outC)
{
    __shared__ float sW[D][D];
    __shared__ float4 sZ4[TILE][17];    // z = x + agg (preserved)
    __shared__ float4 sH4[TILE][17];    // layer-1 output
    __shared__ float sB[D];

    int tid = threadIdx.x;
    int node0 = blockIdx.x * TILE;
    int wave = tid >> 6, lane = tid & 63;
    int g = lane >> 4, q = lane & 15;

    for (int r = wave; r < TILE; r += (TPB / 64)) {
        int n = node0 + r;
        float4 a = gather_row(h4, row_ptr, colv, (n < NN) ? n : -1, g, q);
        if (g == 0) sZ4[r][q] = a;
    }

    int tr = tid >> 4, tc = tid & 15;
    float* zr0 = (float*)&sZ4[tr * 2 + 0][0];
    float* zr1 = (float*)&sZ4[tr * 2 + 1][0];
    float* hr0 = (float*)&sH4[tr * 2 + 0][0];
    float* hr1 = (float*)&sH4[tr * 2 + 1][0];

    #pragma unroll 1
    for (int m = 0; m < 3; ++m) {
        const float* W1 = (m == 0) ? W1a : (m == 1) ? W1b : W1c;
        const float* B1 = (m == 0) ? b1a : (m == 1) ? b1b : b1c;
        const float* W2 = (m == 0) ? W2a : (m == 1) ? W2b : W2c;
        const float* B2 = (m == 0) ? b2a : (m == 1) ? b2b : b2c;
        float4* out4 = (m == 0) ? outA : (m == 1) ? outB : outC;

        load_w(sW, W1, tid);
        if (tid < D) sB[tid] = B1[tid];
        __syncthreads();            // first iteration: also covers the gather

        float acc[2][4];
        acc_init(acc, sB, tc);
        layer_acc(acc, zr0, zr1, sW, tc);
        relu_wb(acc, hr0, hr1, tc);
        __syncthreads();

        load_w(sW, W2, tid);
        if (tid < D) sB[tid] = B2[tid];
        __syncthreads();

        acc_init(acc, sB, tc);
        layer_acc(acc, hr0, hr1, sW, tc);
        store_rows(acc, out4, node0, tr, tc);
        __syncthreads();            // protect sW/sB before next MLP
    }
}

// ---------------- fused pair: H1 = f_a(hA), tC2 = f_b(hB), one edge walk ----------------

__global__ __launch_bounds__(TPB) void k_conv2(
    const float4* __restrict__ hA4, const float4* __restrict__ hB4,
    const int* __restrict__ row_ptr, const int* __restrict__ colv,
    const float* __restrict__ W1a, const float* __restrict__ b1a,
    const float* __restrict__ W2a, const float* __restrict__ b2a,
    const float* __restrict__ W1b, const float* __restrict__ b1b,
    const float* __restrict__ W2b, const float* __restrict__ b2b,
    float4* __restrict__ outA4, float4* __restrict__ outB4)
{
    __shared__ float sW[D][D];
    __shared__ float4 sZa[TILE][17];
    __shared__ float4 sZb[TILE][17];
    __shared__ float sB[D];

    int tid = threadIdx.x;
    int node0 = blockIdx.x * TILE;
    int wave = tid >> 6, lane = tid & 63;
    int g = lane >> 4, q = lane & 15;

    for (int r = wave; r < TILE; r += (TPB / 64)) {
        int n = node0 + r;
        float4 a0 = make_float4(0.f, 0.f, 0.f, 0.f);
        float4 a1 = make_float4(0.f, 0.f, 0.f, 0.f);
        float4 b0 = make_float4(0.f, 0.f, 0.f, 0.f);
        float4 b1v = make_float4(0.f, 0.f, 0.f, 0.f);
        if (n < NN) {
            if (g == 0) { a0 = hA4[n * 16 + q]; b0 = hB4[n * 16 + q]; }
            int e1 = row_ptr[n + 1];
            int e  = row_ptr[n] + g;
            for (; e + 4 < e1; e += 8) {
                int s0 = colv[e], s1 = colv[e + 4];
                float4 va0 = hA4[s0 * 16 + q];
                float4 vb0 = hB4[s0 * 16 + q];
                float4 va1 = hA4[s1 * 16 + q];
                float4 vb1 = hB4[s1 * 16 + q];
                a0.x += va0.x; a0.y += va0.y; a0.z += va0.z; a0.w += va0.w;
                b0.x += vb0.x; b0.y += vb0.y; b0.z += vb0.z; b0.w += vb0.w;
                a1.x += va1.x; a1.y += va1.y; a1.z += va1.z; a1.w += va1.w;
                b1v.x += vb1.x; b1v.y += vb1.y; b1v.z += vb1.z; b1v.w += vb1.w;
            }
            if (e < e1) {
                int s = colv[e];
                float4 va = hA4[s * 16 + q];
                float4 vb = hB4[s * 16 + q];
                a0.x += va.x; a0.y += va.y; a0.z += va.z; a0.w += va.w;
                b0.x += vb.x; b0.y += vb.y; b0.z += vb.z; b0.w += vb.w;
            }
            a0.x += a1.x; a0.y += a1.y; a0.z += a1.z; a0.w += a1.w;
            b0.x += b1v.x; b0.y += b1v.y; b0.z += b1v.z; b0.w += b1v.w;
        }
        a0.x += __shfl_xor(a0.x, 16); a0.y += __shfl_xor(a0.y, 16);
        a0.z += __shfl_xor(a0.z, 16); a0.w += __shfl_xor(a0.w, 16);
        a0.x += __shfl_xor(a0.x, 32); a0.y += __shfl_xor(a0.y, 32);
        a0.z += __shfl_xor(a0.z, 32); a0.w += __shfl_xor(a0.w, 32);
        b0.x += __shfl_xor(b0.x, 16); b0.y += __shfl_xor(b0.y, 16);
        b0.z += __shfl_xor(b0.z, 16); b0.w += __shfl_xor(b0.w, 16);
        b0.x += __shfl_xor(b0.x, 32); b0.y += __shfl_xor(b0.y, 32);
        b0.z += __shfl_xor(b0.z, 32); b0.w += __shfl_xor(b0.w, 32);
        if (g == 0) { sZa[r][q] = a0; sZb[r][q] = b0; }
    }

    int tr = tid >> 4, tc = tid & 15;
    float* zra0 = (float*)&sZa[tr * 2 + 0][0];
    float* zra1 = (float*)&sZa[tr * 2 + 1][0];
    float* zrb0 = (float*)&sZb[tr * 2 + 0][0];
    float* zrb1 = (float*)&sZb[tr * 2 + 1][0];
    float acc[2][4];

    // MLP A
    load_w(sW, W1a, tid); if (tid < D) sB[tid] = b1a[tid];
    __syncthreads();                       // covers gather too
    acc_init(acc, sB, tc);
    layer_acc(acc, zra0, zra1, sW, tc);
    relu_wb(acc, zra0, zra1, tc);          // in place, same-wave safe
    __syncthreads();
    load_w(sW, W2a, tid); if (tid < D) sB[tid] = b2a[tid];
    __syncthreads();
    acc_init(acc, sB, tc);
    layer_acc(acc, zra0, zra1, sW, tc);
    store_rows(acc, outA4, node0, tr, tc);
    __syncthreads();

    // MLP B
    load_w(sW, W1b, tid); if (tid < D) sB[tid] = b1b[tid];
    __syncthreads();
    acc_init(acc, sB, tc);
    layer_acc(acc, zrb0, zrb1, sW, tc);
    relu_wb(acc, zrb0, zrb1, tc);
    __syncthreads();
    load_w(sW, W2b, tid); if (tid < D) sB[tid] = b2b[tid];
    __syncthreads();
    acc_init(acc, sB, tc);
    layer_acc(acc, zrb0, zrb1, sW, tc);
    store_rows(acc, outB4, node0, tr, tc);
}

// ---------------- last conv + final projection fused ----------------
// h2 = f2(h);  out = bo + H0@Wo[0:64] + H1@Wo[64:128] + h2@Wo[128:192]

__global__ __launch_bounds__(TPB) void k_conv_final(
    const float4* __restrict__ h4,
    const float4* __restrict__ H0, const float4* __restrict__ H1,
    const int* __restrict__ row_ptr, const int* __restrict__ colv,
    const float* __restrict__ W1, const float* __restrict__ b1,
    const float* __restrict__ W2, const float* __restrict__ b2,
    const float* __restrict__ Wo, const float* __restrict__ bo,
    float4* __restrict__ out4)
{
    __shared__ float sW[D][D];
    __shared__ float4 sZ4[TILE][17];   // z -> h1 -> h2 (in place)
    __shared__ float4 sY4[TILE][17];   // staging H0 / H1 rows
    __shared__ float sB[D];

    int tid = threadIdx.x;
    int node0 = blockIdx.x * TILE;
    int wave = tid >> 6, lane = tid & 63;
    int g = lane >> 4, q = lane & 15;

    for (int r = wave; r < TILE; r += (TPB / 64)) {
        int n = node0 + r;
        float4 a = gather_row(h4, row_ptr, colv, (n < NN) ? n : -1, g, q);
        if (g == 0) sZ4[r][q] = a;
    }

    int tr = tid >> 4, tc = tid & 15;
    float* zr0 = (float*)&sZ4[tr * 2 + 0][0];
    float* zr1 = (float*)&sZ4[tr * 2 + 1][0];
    float* yr0 = (float*)&sY4[tr * 2 + 0][0];
    float* yr1 = (float*)&sY4[tr * 2 + 1][0];
    float acc[2][4];

    // conv layer 1
    load_w(sW, W1, tid); if (tid < D) sB[tid] = b1[tid];
    __syncthreads();                       // covers gather
    acc_init(acc, sB, tc);
    layer_acc(acc, zr0, zr1, sW, tc);
    relu_wb(acc, zr0, zr1, tc);
    __syncthreads();
    // conv layer 2 (no relu) -> h2 kept in sZ
    load_w(sW, W2, tid); if (tid < D) sB[tid] = b2[tid];
    __syncthreads();
    acc_init(acc, sB, tc);
    layer_acc(acc, zr0, zr1, sW, tc);
    {
        float4 h0v, h1v;
        h0v.x = acc[0][0]; h0v.y = acc[0][1]; h0v.z = acc[0][2]; h0v.w = acc[0][3];
        h1v.x = acc[1][0]; h1v.y = acc[1][1]; h1v.z = acc[1][2]; h1v.w = acc[1][3];
        *(float4*)&zr0[tc * 4] = h0v;
        *(float4*)&zr1[tc * 4] = h1v;
    }
    __syncthreads();

    // projection chunk h2 (Wo rows 128..191); stage H0 concurrently
    load_w(sW, Wo + 128 * D, tid); if (tid < D) sB[tid] = bo[tid];
    for (int i = tid; i < TILE * 16; i += TPB) {
        int r = i >> 4, qq = i & 15;
        int n = node0 + r;
        sY4[r][qq] = (n < NN) ? H0[n * 16 + qq] : make_float4(0.f, 0.f, 0.f, 0.f);
    }
    __syncthreads();
    float accO[2][4];
    acc_init(accO, sB, tc);
    layer_acc(accO, zr0, zr1, sW, tc);
    __syncthreads();

    // chunk H0 (Wo rows 0..63)
    load_w(sW, Wo, tid);
    __syncthreads();
    layer_acc(accO, yr0, yr1, sW, tc);
    __syncthreads();

    // chunk H1 (Wo rows 64..127); restage sY with H1
    load_w(sW, Wo + 64 * D, tid);
    for (int i = tid; i < TILE * 16; i += TPB) {
        int r = i >> 4, qq = i & 15;
        int n = node0 + r;
        sY4[r][qq] = (n < NN) ? H1[n * 16 + qq] : make_float4(0.f, 0.f, 0.f, 0.f);
    }
    __syncthreads();
    layer_acc(accO, yr0, yr1, sW, tc);

    store_rows(accO, out4, node0, tr, tc);
}

// ---------------- launch ----------------

extern "C" void kernel_launch(void* const* d_in, const int* in_sizes, int n_in,
                              void* d_out, int out_size, void* d_ws, size_t ws_size,
                              hipStream_t stream) {
    const float* x    = (const float*)d_in[0];
    const int*   ei   = (const int*)d_in[1];   // [2, NE] int32
    const float* W1_0 = (const float*)d_in[2];
    const float* b1_0 = (const float*)d_in[3];
    const float* W2_0 = (const float*)d_in[4];
    const float* b2_0 = (const float*)d_in[5];
    const float* W1_1 = (const float*)d_in[6];
    const float* b1_1 = (const float*)d_in[7];
    const float* W2_1 = (const float*)d_in[8];
    const float* b2_1 = (const float*)d_in[9];
    const float* W1_2 = (const float*)d_in[10];
    const float* b1_2 = (const float*)d_in[11];
    const float* W2_2 = (const float*)d_in[12];
    const float* b2_2 = (const float*)d_in[13];
    const float* Wo   = (const float*)d_in[14];
    const float* bo   = (const float*)d_in[15];
    float4* out = (float4*)d_out;

    char* ws = (char*)d_ws;
    int* deg     = (int*)(ws + 0);
    int* cursor  = (int*)(ws + 200704);
    int* row_ptr = (int*)(ws + 401408);
    int* colv    = (int*)(ws + 602112);
    int* bsum    = (int*)(ws + 3802112);
    int* boff    = (int*)(ws + 3803136);
    float* fbase = (float*)(ws + 3804160);
    float4* H0  = (float4*)(fbase);
    float4* H1  = (float4*)(fbase + 3200000);
    float4* tB  = (float4*)(fbase + 6400000);
    float4* tC2 = (float4*)(fbase + 9600000);
    const float4* x4 = (const float4*)x;

    // CSR build
    hipMemsetAsync(deg, 0, NN * sizeof(int), stream);
    k_count<<<(NE + 255) / 256, 256, 0, stream>>>(ei, deg);
    k_bsum <<<NBLK, 256, 0, stream>>>(deg, bsum);
    k_boff <<<1, 256, 0, stream>>>(bsum, boff, row_ptr);
    k_scan2<<<NBLK, 256, 0, stream>>>(deg, boff, row_ptr, cursor);
    k_fill <<<(NE + 255) / 256, 256, 0, stream>>>(ei, cursor, colv);

    int nb = (NN + TILE - 1) / TILE;  // 782

    // one gather of x, three MLPs: H0 = f0(x), tB = f1(x), out = f2(x)
    k_aggmlp3<<<nb, TPB, 0, stream>>>(x4, row_ptr, colv,
                                      W1_0, b1_0, W2_0, b2_0,
                                      W1_1, b1_1, W2_1, b2_1,
                                      W1_2, b1_2, W2_2, b2_2,
                                      H0, tB, out);

    // fused pair: H1 = f1(tB), tC2 = f2(out)
    k_conv2<<<nb, TPB, 0, stream>>>(tB, (const float4*)out, row_ptr, colv,
                                    W1_1, b1_1, W2_1, b2_1,
                                    W1_2, b1_2, W2_2, b2_2,
                                    H1, tC2);

    // last conv + final projection fused
    k_conv_final<<<nb, TPB, 0, stream>>>((const float4*)tC2,
                                         (const float4*)H0, (const float4*)H1,
                                         row_ptr, colv,
                                         W1_2, b1_2, W2_2, b2_2,
                                         Wo, bo, out);
}

// Round 5
// 428.286 us; speedup vs baseline: 1.1739x; 1.1739x over previous
//
#include <hip/hip_runtime.h>

#define NN 50000
#define NE 800000
#define D  64
#define TILE 64
#define TPB 512
#define NBLK 196   // ceil(NN/256)

// ---------------- CSR build ----------------

__global__ __launch_bounds__(256) void k_count(const int* __restrict__ ei, int* __restrict__ deg) {
    int e = blockIdx.x * 256 + threadIdx.x;
    if (e < NE) atomicAdd(&deg[ei[NE + e]], 1);
}

__global__ __launch_bounds__(256) void k_bsum(const int* __restrict__ deg, int* __restrict__ bsum) {
    __shared__ int s[256];
    int t = threadIdx.x;
    int i = blockIdx.x * 256 + t;
    s[t] = (i < NN) ? deg[i] : 0;
    __syncthreads();
    for (int off = 128; off > 0; off >>= 1) {
        if (t < off) s[t] += s[t + off];
        __syncthreads();
    }
    if (t == 0) bsum[blockIdx.x] = s[0];
}

__global__ __launch_bounds__(256) void k_boff(const int* __restrict__ bsum,
                                              int* __restrict__ boff,
                                              int* __restrict__ row_ptr) {
    __shared__ int s[256];
    int t = threadIdx.x;
    int v = (t < NBLK) ? bsum[t] : 0;
    s[t] = v;
    __syncthreads();
    for (int off = 1; off < 256; off <<= 1) {
        int u = (t >= off) ? s[t - off] : 0;
        __syncthreads();
        s[t] += u;
        __syncthreads();
    }
    boff[t] = s[t] - v;
    if (t == 0) row_ptr[NN] = NE;
}

__global__ __launch_bounds__(256) void k_scan2(const int* __restrict__ deg,
                                               const int* __restrict__ boff,
                                               int* __restrict__ row_ptr,
                                               int* __restrict__ cursor) {
    __shared__ int s[256];
    int t = threadIdx.x;
    int i = blockIdx.x * 256 + t;
    int v = (i < NN) ? deg[i] : 0;
    s[t] = v;
    __syncthreads();
    for (int off = 1; off < 256; off <<= 1) {
        int u = (t >= off) ? s[t - off] : 0;
        __syncthreads();
        s[t] += u;
        __syncthreads();
    }
    int excl = s[t] - v + boff[blockIdx.x];
    if (i < NN) { row_ptr[i] = excl; cursor[i] = excl; }
}

__global__ __launch_bounds__(256) void k_fill(const int* __restrict__ ei,
                                              int* __restrict__ cursor,
                                              int* __restrict__ colv) {
    int e = blockIdx.x * 256 + threadIdx.x;
    if (e < NE) {
        int d = ei[NE + e];
        int p = atomicAdd(&cursor[d], 1);
        colv[p] = ei[e];
    }
}

// ---------------- gather helper (device inline; round-3 proven codegen) ----------------

__device__ __forceinline__ float4 gather_row(const float4* __restrict__ h4,
                                             const int* __restrict__ row_ptr,
                                             const int* __restrict__ colv,
                                             int n, int g, int q) {
    float4 a0 = make_float4(0.f, 0.f, 0.f, 0.f);
    float4 a1 = make_float4(0.f, 0.f, 0.f, 0.f);
    float4 a2 = make_float4(0.f, 0.f, 0.f, 0.f);
    float4 a3 = make_float4(0.f, 0.f, 0.f, 0.f);
    if (n >= 0) {
        if (g == 0) a0 = h4[n * 16 + q];           // self term
        int e1 = row_ptr[n + 1];
        int e  = row_ptr[n] + g;
        for (; e + 12 < e1; e += 16) {
            int s0 = colv[e], s1 = colv[e + 4], s2 = colv[e + 8], s3 = colv[e + 12];
            float4 v0 = h4[s0 * 16 + q];
            float4 v1 = h4[s1 * 16 + q];
            float4 v2 = h4[s2 * 16 + q];
            float4 v3 = h4[s3 * 16 + q];
            a0.x += v0.x; a0.y += v0.y; a0.z += v0.z; a0.w += v0.w;
            a1.x += v1.x; a1.y += v1.y; a1.z += v1.z; a1.w += v1.w;
            a2.x += v2.x; a2.y += v2.y; a2.z += v2.z; a2.w += v2.w;
            a3.x += v3.x; a3.y += v3.y; a3.z += v3.z; a3.w += v3.w;
        }
        for (; e < e1; e += 4) {
            float4 v = h4[colv[e] * 16 + q];
            a1.x += v.x; a1.y += v.y; a1.z += v.z; a1.w += v.w;
        }
        a0.x += a1.x + a2.x + a3.x;
        a0.y += a1.y + a2.y + a3.y;
        a0.z += a1.z + a2.z + a3.z;
        a0.w += a1.w + a2.w + a3.w;
    }
    // combine the 4 groups (wave-uniform control)
    a0.x += __shfl_xor(a0.x, 16); a0.y += __shfl_xor(a0.y, 16);
    a0.z += __shfl_xor(a0.z, 16); a0.w += __shfl_xor(a0.w, 16);
    a0.x += __shfl_xor(a0.x, 32); a0.y += __shfl_xor(a0.y, 32);
    a0.z += __shfl_xor(a0.z, 32); a0.w += __shfl_xor(a0.w, 32);
    return a0;
}

// ---------------- fused GIN conv: out = MLP(h + sum h[src]) — round-3 verbatim ----------------

__global__ __launch_bounds__(TPB) void k_conv(
    const float4* __restrict__ h4,
    const int* __restrict__ row_ptr,
    const int* __restrict__ colv,
    const float* __restrict__ W1, const float* __restrict__ b1,
    const float* __restrict__ W2, const float* __restrict__ b2,
    float4* __restrict__ out4)
{
    __shared__ float sW1[D][D];
    __shared__ float sW2[D][D];
    __shared__ float4 sZ4[TILE][17];
    __shared__ float sB1[D], sB2[D];

    int tid = threadIdx.x;
    int node0 = blockIdx.x * TILE;

    {
        const float4* w14 = (const float4*)W1;
        const float4* w24 = (const float4*)W2;
        float4* s14 = (float4*)sW1;
        float4* s24 = (float4*)sW2;
        for (int i = tid; i < D * D / 4; i += TPB) { s14[i] = w14[i]; s24[i] = w24[i]; }
        if (tid < D) { sB1[tid] = b1[tid]; sB2[tid] = b2[tid]; }
    }

    int wave = tid >> 6, lane = tid & 63;
    int g = lane >> 4, q = lane & 15;

    for (int r = wave; r < TILE; r += (TPB / 64)) {
        int n = node0 + r;
        float4 a = gather_row(h4, row_ptr, colv, (n < NN) ? n : -1, g, q);
        if (g == 0) sZ4[r][q] = a;
    }
    __syncthreads();

    // MLP with same-wave in-place writeback (row owned by one 16-thread group)
    int tr = tid >> 4, tc = tid & 15;
    float* zr0 = (float*)&sZ4[tr * 2 + 0][0];
    float* zr1 = (float*)&sZ4[tr * 2 + 1][0];

    float acc[2][4];
    #pragma unroll
    for (int c = 0; c < 4; ++c) { acc[0][c] = sB1[tc * 4 + c]; acc[1][c] = sB1[tc * 4 + c]; }
    #pragma unroll 16
    for (int k = 0; k < D; ++k) {
        float z0 = zr0[k], z1 = zr1[k];
        #pragma unroll
        for (int c = 0; c < 4; ++c) {
            float w = sW1[k][tc * 4 + c];
            acc[0][c] += z0 * w;
            acc[1][c] += z1 * w;
        }
    }
    {
        float4 h0, h1;
        h0.x = fmaxf(acc[0][0], 0.f); h0.y = fmaxf(acc[0][1], 0.f);
        h0.z = fmaxf(acc[0][2], 0.f); h0.w = fmaxf(acc[0][3], 0.f);
        h1.x = fmaxf(acc[1][0], 0.f); h1.y = fmaxf(acc[1][1], 0.f);
        h1.z = fmaxf(acc[1][2], 0.f); h1.w = fmaxf(acc[1][3], 0.f);
        *(float4*)&zr0[tc * 4] = h0;
        *(float4*)&zr1[tc * 4] = h1;
    }
    #pragma unroll
    for (int c = 0; c < 4; ++c) { acc[0][c] = sB2[tc * 4 + c]; acc[1][c] = sB2[tc * 4 + c]; }
    #pragma unroll 16
    for (int k = 0; k < D; ++k) {
        float z0 = zr0[k], z1 = zr1[k];
        #pragma unroll
        for (int c = 0; c < 4; ++c) {
            float w = sW2[k][tc * 4 + c];
            acc[0][c] += z0 * w;
            acc[1][c] += z1 * w;
        }
    }
    #pragma unroll
    for (int i = 0; i < 2; ++i) {
        int n = node0 + tr * 2 + i;
        if (n < NN) {
            float4 o;
            o.x = acc[i][0]; o.y = acc[i][1]; o.z = acc[i][2]; o.w = acc[i][3];
            out4[n * 16 + tc] = o;
        }
    }
}

// ---------------- one gather of x, three MLPs (params 0/1/2) — round-3 verbatim ----------------

__global__ __launch_bounds__(TPB) void k_aggmlp3(
    const float4* __restrict__ h4,
    const int* __restrict__ row_ptr,
    const int* __restrict__ colv,
    const float* __restrict__ W1a, const float* __restrict__ b1a,
    const float* __restrict__ W2a, const float* __restrict__ b2a,
    const float* __restrict__ W1b, const float* __restrict__ b1b,
    const float* __restrict__ W2b, const float* __restrict__ b2b,
    const float* __restrict__ W1c, const float* __restrict__ b1c,
    const float* __restrict__ W2c, const float* __restrict__ b2c,
    float4* __restrict__ outA, float4* __restrict__ outB, float4* __restrict__ outC)
{
    __shared__ float sW[D][D];          // 16 KB, reloaded per layer
    __shared__ float4 sZ4[TILE][17];    // z = x + agg (preserved)
    __shared__ float4 sH4[TILE][17];    // layer-1 output
    __shared__ float sB[D];

    int tid = threadIdx.x;
    int node0 = blockIdx.x * TILE;

    int wave = tid >> 6, lane = tid & 63;
    int g = lane >> 4, q = lane & 63 & 15;

    for (int r = wave; r < TILE; r += (TPB / 64)) {
        int n = node0 + r;
        float4 a = gather_row(h4, row_ptr, colv, (n < NN) ? n : -1, g, q);
        if (g == 0) sZ4[r][q] = a;
    }

    int tr = tid >> 4, tc = tid & 15;
    float* zr0 = (float*)&sZ4[tr * 2 + 0][0];
    float* zr1 = (float*)&sZ4[tr * 2 + 1][0];
    float* hr0 = (float*)&sH4[tr * 2 + 0][0];
    float* hr1 = (float*)&sH4[tr * 2 + 1][0];

    #pragma unroll 1
    for (int m = 0; m < 3; ++m) {
        const float* W1 = (m == 0) ? W1a : (m == 1) ? W1b : W1c;
        const float* B1 = (m == 0) ? b1a : (m == 1) ? b1b : b1c;
        const float* W2 = (m == 0) ? W2a : (m == 1) ? W2b : W2c;
        const float* B2 = (m == 0) ? b2a : (m == 1) ? b2b : b2c;
        float4* out4 = (m == 0) ? outA : (m == 1) ? outB : outC;

        // load W1, b1 (first iteration's sync also covers the gather)
        {
            const float4* w4 = (const float4*)W1;
            float4* s4 = (float4*)sW;
            for (int i = tid; i < D * D / 4; i += TPB) s4[i] = w4[i];
            if (tid < D) sB[tid] = B1[tid];
        }
        __syncthreads();

        float acc[2][4];
        #pragma unroll
        for (int c = 0; c < 4; ++c) { acc[0][c] = sB[tc * 4 + c]; acc[1][c] = sB[tc * 4 + c]; }
        #pragma unroll 16
        for (int k = 0; k < D; ++k) {
            float z0 = zr0[k], z1 = zr1[k];
            #pragma unroll
            for (int c = 0; c < 4; ++c) {
                float w = sW[k][tc * 4 + c];
                acc[0][c] += z0 * w;
                acc[1][c] += z1 * w;
            }
        }
        {
            float4 h0, h1;
            h0.x = fmaxf(acc[0][0], 0.f); h0.y = fmaxf(acc[0][1], 0.f);
            h0.z = fmaxf(acc[0][2], 0.f); h0.w = fmaxf(acc[0][3], 0.f);
            h1.x = fmaxf(acc[1][0], 0.f); h1.y = fmaxf(acc[1][1], 0.f);
            h1.z = fmaxf(acc[1][2], 0.f); h1.w = fmaxf(acc[1][3], 0.f);
            *(float4*)&hr0[tc * 4] = h0;
            *(float4*)&hr1[tc * 4] = h1;
        }
        __syncthreads();

        // load W2, b2
        {
            const float4* w4 = (const float4*)W2;
            float4* s4 = (float4*)sW;
            for (int i = tid; i < D * D / 4; i += TPB) s4[i] = w4[i];
            if (tid < D) sB[tid] = B2[tid];
        }
        __syncthreads();

        #pragma unroll
        for (int c = 0; c < 4; ++c) { acc[0][c] = sB[tc * 4 + c]; acc[1][c] = sB[tc * 4 + c]; }
        #pragma unroll 16
        for (int k = 0; k < D; ++k) {
            float h0 = hr0[k], h1 = hr1[k];
            #pragma unroll
            for (int c = 0; c < 4; ++c) {
                float w = sW[k][tc * 4 + c];
                acc[0][c] += h0 * w;
                acc[1][c] += h1 * w;
            }
        }
        #pragma unroll
        for (int i = 0; i < 2; ++i) {
            int n = node0 + tr * 2 + i;
            if (n < NN) {
                float4 o;
                o.x = acc[i][0]; o.y = acc[i][1]; o.z = acc[i][2]; o.w = acc[i][3];
                out4[n * 16 + tc] = o;
            }
        }
        __syncthreads();   // protect sW/sB before next MLP's load
    }
}

// ---------------- last conv + final projection fused ----------------
// h2 = f2(h);  out = bo + h2@Wo[128:192] + H0@Wo[0:64] + H1@Wo[64:128]

__global__ __launch_bounds__(TPB) void k_conv_final(
    const float4* __restrict__ h4,
    const float4* __restrict__ H0, const float4* __restrict__ H1,
    const int* __restrict__ row_ptr, const int* __restrict__ colv,
    const float* __restrict__ W1, const float* __restrict__ b1,
    const float* __restrict__ W2, const float* __restrict__ b2,
    const float* __restrict__ Wo, const float* __restrict__ bo,
    float4* __restrict__ out4)
{
    __shared__ float sW[D][D];          // reloaded: W1, W2, Wo2, Wo0, Wo1
    __shared__ float4 sZ4[TILE][17];    // z -> h1 -> h2 (in place)
    __shared__ float4 sY4[TILE][17];    // staging H0 then H1
    __shared__ float sB[D];

    int tid = threadIdx.x;
    int node0 = blockIdx.x * TILE;
    int wave = tid >> 6, lane = tid & 63;
    int g = lane >> 4, q = lane & 15;

    for (int r = wave; r < TILE; r += (TPB / 64)) {
        int n = node0 + r;
        float4 a = gather_row(h4, row_ptr, colv, (n < NN) ? n : -1, g, q);
        if (g == 0) sZ4[r][q] = a;
    }

    int tr = tid >> 4, tc = tid & 15;
    float* zr0 = (float*)&sZ4[tr * 2 + 0][0];
    float* zr1 = (float*)&sZ4[tr * 2 + 1][0];
    float* yr0 = (float*)&sY4[tr * 2 + 0][0];
    float* yr1 = (float*)&sY4[tr * 2 + 1][0];

    // ---- conv layer 1 ----
    {
        const float4* w4 = (const float4*)W1;
        float4* s4 = (float4*)sW;
        for (int i = tid; i < D * D / 4; i += TPB) s4[i] = w4[i];
        if (tid < D) sB[tid] = b1[tid];
    }
    __syncthreads();                       // also covers gather

    float acc[2][4];
    #pragma unroll
    for (int c = 0; c < 4; ++c) { acc[0][c] = sB[tc * 4 + c]; acc[1][c] = sB[tc * 4 + c]; }
    #pragma unroll 16
    for (int k = 0; k < D; ++k) {
        float z0 = zr0[k], z1 = zr1[k];
        #pragma unroll
        for (int c = 0; c < 4; ++c) {
            float w = sW[k][tc * 4 + c];
            acc[0][c] += z0 * w;
            acc[1][c] += z1 * w;
        }
    }
    {
        float4 h0, h1;
        h0.x = fmaxf(acc[0][0], 0.f); h0.y = fmaxf(acc[0][1], 0.f);
        h0.z = fmaxf(acc[0][2], 0.f); h0.w = fmaxf(acc[0][3], 0.f);
        h1.x = fmaxf(acc[1][0], 0.f); h1.y = fmaxf(acc[1][1], 0.f);
        h1.z = fmaxf(acc[1][2], 0.f); h1.w = fmaxf(acc[1][3], 0.f);
        *(float4*)&zr0[tc * 4] = h0;       // same-wave in-place, safe
        *(float4*)&zr1[tc * 4] = h1;
    }
    __syncthreads();

    // ---- conv layer 2 (no relu), h2 kept in sZ ----
    {
        const float4* w4 = (const float4*)W2;
        float4* s4 = (float4*)sW;
        for (int i = tid; i < D * D / 4; i += TPB) s4[i] = w4[i];
        if (tid < D) sB[tid] = b2[tid];
    }
    __syncthreads();

    #pragma unroll
    for (int c = 0; c < 4; ++c) { acc[0][c] = sB[tc * 4 + c]; acc[1][c] = sB[tc * 4 + c]; }
    #pragma unroll 16
    for (int k = 0; k < D; ++k) {
        float z0 = zr0[k], z1 = zr1[k];
        #pragma unroll
        for (int c = 0; c < 4; ++c) {
            float w = sW[k][tc * 4 + c];
            acc[0][c] += z0 * w;
            acc[1][c] += z1 * w;
        }
    }
    {
        float4 h0, h1;
        h0.x = acc[0][0]; h0.y = acc[0][1]; h0.z = acc[0][2]; h0.w = acc[0][3];
        h1.x = acc[1][0]; h1.y = acc[1][1]; h1.z = acc[1][2]; h1.w = acc[1][3];
        *(float4*)&zr0[tc * 4] = h0;
        *(float4*)&zr1[tc * 4] = h1;
    }
    __syncthreads();

    // ---- projection chunk h2 (Wo rows 128..191); stage H0 concurrently ----
    {
        const float4* w4 = (const float4*)(Wo + 128 * D);
        float4* s4 = (float4*)sW;
        for (int i = tid; i < D * D / 4; i += TPB) s4[i] = w4[i];
        if (tid < D) sB[tid] = bo[tid];
    }
    for (int i = tid; i < TILE * 16; i += TPB) {
        int r = i >> 4, qq = i & 15;
        int n = node0 + r;
        sY4[r][qq] = (n < NN) ? H0[n * 16 + qq] : make_float4(0.f, 0.f, 0.f, 0.f);
    }
    __syncthreads();

    float accO[2][4];
    #pragma unroll
    for (int c = 0; c < 4; ++c) { accO[0][c] = sB[tc * 4 + c]; accO[1][c] = sB[tc * 4 + c]; }
    #pragma unroll 16
    for (int k = 0; k < D; ++k) {
        float z0 = zr0[k], z1 = zr1[k];
        #pragma unroll
        for (int c = 0; c < 4; ++c) {
            float w = sW[k][tc * 4 + c];
            accO[0][c] += z0 * w;
            accO[1][c] += z1 * w;
        }
    }
    __syncthreads();

    // ---- chunk H0 (Wo rows 0..63) ----
    {
        const float4* w4 = (const float4*)Wo;
        float4* s4 = (float4*)sW;
        for (int i = tid; i < D * D / 4; i += TPB) s4[i] = w4[i];
    }
    __syncthreads();
    #pragma unroll 16
    for (int k = 0; k < D; ++k) {
        float z0 = yr0[k], z1 = yr1[k];
        #pragma unroll
        for (int c = 0; c < 4; ++c) {
            float w = sW[k][tc * 4 + c];
            accO[0][c] += z0 * w;
            accO[1][c] += z1 * w;
        }
    }
    __syncthreads();

    // ---- chunk H1 (Wo rows 64..127); restage sY with H1 ----
    {
        const float4* w4 = (const float4*)(Wo + 64 * D);
        float4* s4 = (float4*)sW;
        for (int i = tid; i < D * D / 4; i += TPB) s4[i] = w4[i];
    }
    for (int i = tid; i < TILE * 16; i += TPB) {
        int r = i >> 4, qq = i & 15;
        int n = node0 + r;
        sY4[r][qq] = (n < NN) ? H1[n * 16 + qq] : make_float4(0.f, 0.f, 0.f, 0.f);
    }
    __syncthreads();
    #pragma unroll 16
    for (int k = 0; k < D; ++k) {
        float z0 = yr0[k], z1 = yr1[k];
        #pragma unroll
        for (int c = 0; c < 4; ++c) {
            float w = sW[k][tc * 4 + c];
            accO[0][c] += z0 * w;
            accO[1][c] += z1 * w;
        }
    }

    #pragma unroll
    for (int i = 0; i < 2; ++i) {
        int n = node0 + tr * 2 + i;
        if (n < NN) {
            float4 o;
            o.x = accO[i][0]; o.y = accO[i][1]; o.z = accO[i][2]; o.w = accO[i][3];
            out4[n * 16 + tc] = o;
        }
    }
}

// ---------------- launch ----------------

extern "C" void kernel_launch(void* const* d_in, const int* in_sizes, int n_in,
                              void* d_out, int out_size, void* d_ws, size_t ws_size,
                              hipStream_t stream) {
    const float* x    = (const float*)d_in[0];
    const int*   ei   = (const int*)d_in[1];   // [2, NE] int32
    const float* W1_0 = (const float*)d_in[2];
    const float* b1_0 = (const float*)d_in[3];
    const float* W2_0 = (const float*)d_in[4];
    const float* b2_0 = (const float*)d_in[5];
    const float* W1_1 = (const float*)d_in[6];
    const float* b1_1 = (const float*)d_in[7];
    const float* W2_1 = (const float*)d_in[8];
    const float* b2_1 = (const float*)d_in[9];
    const float* W1_2 = (const float*)d_in[10];
    const float* b1_2 = (const float*)d_in[11];
    const float* W2_2 = (const float*)d_in[12];
    const float* b2_2 = (const float*)d_in[13];
    const float* Wo   = (const float*)d_in[14];
    const float* bo   = (const float*)d_in[15];
    float4* out = (float4*)d_out;

    char* ws = (char*)d_ws;
    int* deg     = (int*)(ws + 0);
    int* cursor  = (int*)(ws + 200704);
    int* row_ptr = (int*)(ws + 401408);
    int* colv    = (int*)(ws + 602112);
    int* bsum    = (int*)(ws + 3802112);
    int* boff    = (int*)(ws + 3803136);
    float* fbase = (float*)(ws + 3804160);
    float4* H0  = (float4*)(fbase);
    float4* H1  = (float4*)(fbase + 3200000);
    float4* tB  = (float4*)(fbase + 6400000);
    float4* tC2 = (float4*)(fbase + 9600000);
    const float4* x4 = (const float4*)x;

    // CSR build
    hipMemsetAsync(deg, 0, NN * sizeof(int), stream);
    k_count<<<(NE + 255) / 256, 256, 0, stream>>>(ei, deg);
    k_bsum <<<NBLK, 256, 0, stream>>>(deg, bsum);
    k_boff <<<1, 256, 0, stream>>>(bsum, boff, row_ptr);
    k_scan2<<<NBLK, 256, 0, stream>>>(deg, boff, row_ptr, cursor);
    k_fill <<<(NE + 255) / 256, 256, 0, stream>>>(ei, cursor, colv);

    int nb = (NN + TILE - 1) / TILE;  // 782

    // one gather of x, three MLPs: H0 = f0(x), tB = f1(x), out = f2(x)
    k_aggmlp3<<<nb, TPB, 0, stream>>>(x4, row_ptr, colv,
                                      W1_0, b1_0, W2_0, b2_0,
                                      W1_1, b1_1, W2_1, b2_1,
                                      W1_2, b1_2, W2_2, b2_2,
                                      H0, tB, out);

    // hop-2 tail: H1 = f1(tB)
    k_conv<<<nb, TPB, 0, stream>>>((const float4*)tB, row_ptr, colv,
                                   W1_1, b1_1, W2_1, b2_1, H1);

    // hop-3 middle: tC2 = f2(out)
    k_conv<<<nb, TPB, 0, stream>>>((const float4*)out, row_ptr, colv,
                                   W1_2, b1_2, W2_2, b2_2, tC2);

    // hop-3 last conv + final projection fused
    k_conv_final<<<nb, TPB, 0, stream>>>((const float4*)tC2,
                                         (const float4*)H0, (const float4*)H1,
                                         row_ptr, colv,
                                         W1_2, b1_2, W2_2, b2_2,
                                         Wo, bo, out);
}

// Round 6
// 348.059 us; speedup vs baseline: 1.4445x; 1.2305x over previous
//
#include <hip/hip_runtime.h>

#define NN 50000
#define NE 800000
#define D  64
#define TILE 64
#define TPB 512
#define NBLK 196   // ceil(NN/256)

// ---------------- CSR build ----------------

__global__ __launch_bounds__(256) void k_count(const int* __restrict__ ei, int* __restrict__ deg) {
    int e = blockIdx.x * 256 + threadIdx.x;
    if (e < NE) atomicAdd(&deg[ei[NE + e]], 1);
}

__global__ __launch_bounds__(256) void k_bsum(const int* __restrict__ deg, int* __restrict__ bsum) {
    __shared__ int s[256];
    int t = threadIdx.x;
    int i = blockIdx.x * 256 + t;
    s[t] = (i < NN) ? deg[i] : 0;
    __syncthreads();
    for (int off = 128; off > 0; off >>= 1) {
        if (t < off) s[t] += s[t + off];
        __syncthreads();
    }
    if (t == 0) bsum[blockIdx.x] = s[0];
}

__global__ __launch_bounds__(256) void k_boff(const int* __restrict__ bsum,
                                              int* __restrict__ boff,
                                              int* __restrict__ row_ptr) {
    __shared__ int s[256];
    int t = threadIdx.x;
    int v = (t < NBLK) ? bsum[t] : 0;
    s[t] = v;
    __syncthreads();
    for (int off = 1; off < 256; off <<= 1) {
        int u = (t >= off) ? s[t - off] : 0;
        __syncthreads();
        s[t] += u;
        __syncthreads();
    }
    boff[t] = s[t] - v;
    if (t == 0) row_ptr[NN] = NE;
}

__global__ __launch_bounds__(256) void k_scan2(const int* __restrict__ deg,
                                               const int* __restrict__ boff,
                                               int* __restrict__ row_ptr,
                                               int* __restrict__ cursor) {
    __shared__ int s[256];
    int t = threadIdx.x;
    int i = blockIdx.x * 256 + t;
    int v = (i < NN) ? deg[i] : 0;
    s[t] = v;
    __syncthreads();
    for (int off = 1; off < 256; off <<= 1) {
        int u = (t >= off) ? s[t - off] : 0;
        __syncthreads();
        s[t] += u;
        __syncthreads();
    }
    int excl = s[t] - v + boff[blockIdx.x];
    if (i < NN) { row_ptr[i] = excl; cursor[i] = excl; }
}

__global__ __launch_bounds__(256) void k_fill(const int* __restrict__ ei,
                                              int* __restrict__ cursor,
                                              int* __restrict__ colv) {
    int e = blockIdx.x * 256 + threadIdx.x;
    if (e < NE) {
        int d = ei[NE + e];
        int p = atomicAdd(&cursor[d], 1);
        colv[p] = ei[e];
    }
}

// ---------------- gather helper (device inline; round-3 proven codegen) ----------------

__device__ __forceinline__ float4 gather_row(const float4* __restrict__ h4,
                                             const int* __restrict__ row_ptr,
                                             const int* __restrict__ colv,
                                             int n, int g, int q) {
    float4 a0 = make_float4(0.f, 0.f, 0.f, 0.f);
    float4 a1 = make_float4(0.f, 0.f, 0.f, 0.f);
    float4 a2 = make_float4(0.f, 0.f, 0.f, 0.f);
    float4 a3 = make_float4(0.f, 0.f, 0.f, 0.f);
    if (n >= 0) {
        if (g == 0) a0 = h4[n * 16 + q];           // self term
        int e1 = row_ptr[n + 1];
        int e  = row_ptr[n] + g;
        for (; e + 12 < e1; e += 16) {
            int s0 = colv[e], s1 = colv[e + 4], s2 = colv[e + 8], s3 = colv[e + 12];
            float4 v0 = h4[s0 * 16 + q];
            float4 v1 = h4[s1 * 16 + q];
            float4 v2 = h4[s2 * 16 + q];
            float4 v3 = h4[s3 * 16 + q];
            a0.x += v0.x; a0.y += v0.y; a0.z += v0.z; a0.w += v0.w;
            a1.x += v1.x; a1.y += v1.y; a1.z += v1.z; a1.w += v1.w;
            a2.x += v2.x; a2.y += v2.y; a2.z += v2.z; a2.w += v2.w;
            a3.x += v3.x; a3.y += v3.y; a3.z += v3.z; a3.w += v3.w;
        }
        for (; e < e1; e += 4) {
            float4 v = h4[colv[e] * 16 + q];
            a1.x += v.x; a1.y += v.y; a1.z += v.z; a1.w += v.w;
        }
        a0.x += a1.x + a2.x + a3.x;
        a0.y += a1.y + a2.y + a3.y;
        a0.z += a1.z + a2.z + a3.z;
        a0.w += a1.w + a2.w + a3.w;
    }
    // combine the 4 groups (wave-uniform control)
    a0.x += __shfl_xor(a0.x, 16); a0.y += __shfl_xor(a0.y, 16);
    a0.z += __shfl_xor(a0.z, 16); a0.w += __shfl_xor(a0.w, 16);
    a0.x += __shfl_xor(a0.x, 32); a0.y += __shfl_xor(a0.y, 32);
    a0.z += __shfl_xor(a0.z, 32); a0.w += __shfl_xor(a0.w, 32);
    return a0;
}

// ---------------- fused GIN conv: out = MLP(h + sum h[src]) ----------------
// Single reloaded weight buffer: LDS = 16K(sW) + 17K(sZ) + 0.5K = 34.3 KB
// -> 4 blocks/CU (vs 3 with both weights resident). VGPR pinned <= 64.

__global__ __launch_bounds__(TPB, 8) void k_conv(
    const float4* __restrict__ h4,
    const int* __restrict__ row_ptr,
    const int* __restrict__ colv,
    const float* __restrict__ W1, const float* __restrict__ b1,
    const float* __restrict__ W2, const float* __restrict__ b2,
    float4* __restrict__ out4)
{
    __shared__ float sW[D][D];         // W1 then W2
    __shared__ float4 sZ4[TILE][17];   // z -> h1 (in place)
    __shared__ float sB1[D], sB2[D];

    int tid = threadIdx.x;
    int node0 = blockIdx.x * TILE;

    {
        const float4* w14 = (const float4*)W1;
        float4* s14 = (float4*)sW;
        for (int i = tid; i < D * D / 4; i += TPB) s14[i] = w14[i];
        if (tid < D) { sB1[tid] = b1[tid]; sB2[tid] = b2[tid]; }
    }

    int wave = tid >> 6, lane = tid & 63;
    int g = lane >> 4, q = lane & 15;

    for (int r = wave; r < TILE; r += (TPB / 64)) {
        int n = node0 + r;
        float4 a = gather_row(h4, row_ptr, colv, (n < NN) ? n : -1, g, q);
        if (g == 0) sZ4[r][q] = a;
    }
    __syncthreads();    // covers W1 preload + gather

    // layer 1 with same-wave in-place writeback (row owned by one 16-thread group)
    int tr = tid >> 4, tc = tid & 15;
    float* zr0 = (float*)&sZ4[tr * 2 + 0][0];
    float* zr1 = (float*)&sZ4[tr * 2 + 1][0];

    float acc[2][4];
    #pragma unroll
    for (int c = 0; c < 4; ++c) { acc[0][c] = sB1[tc * 4 + c]; acc[1][c] = sB1[tc * 4 + c]; }
    #pragma unroll 16
    for (int k = 0; k < D; ++k) {
        float z0 = zr0[k], z1 = zr1[k];
        #pragma unroll
        for (int c = 0; c < 4; ++c) {
            float w = sW[k][tc * 4 + c];
            acc[0][c] += z0 * w;
            acc[1][c] += z1 * w;
        }
    }
    {
        float4 h0, h1;
        h0.x = fmaxf(acc[0][0], 0.f); h0.y = fmaxf(acc[0][1], 0.f);
        h0.z = fmaxf(acc[0][2], 0.f); h0.w = fmaxf(acc[0][3], 0.f);
        h1.x = fmaxf(acc[1][0], 0.f); h1.y = fmaxf(acc[1][1], 0.f);
        h1.z = fmaxf(acc[1][2], 0.f); h1.w = fmaxf(acc[1][3], 0.f);
        *(float4*)&zr0[tc * 4] = h0;
        *(float4*)&zr1[tc * 4] = h1;
    }
    __syncthreads();    // all L1 reads of sW done

    {
        const float4* w24 = (const float4*)W2;
        float4* s24 = (float4*)sW;
        for (int i = tid; i < D * D / 4; i += TPB) s24[i] = w24[i];
    }
    __syncthreads();    // W2 visible

    #pragma unroll
    for (int c = 0; c < 4; ++c) { acc[0][c] = sB2[tc * 4 + c]; acc[1][c] = sB2[tc * 4 + c]; }
    #pragma unroll 16
    for (int k = 0; k < D; ++k) {
        float z0 = zr0[k], z1 = zr1[k];
        #pragma unroll
        for (int c = 0; c < 4; ++c) {
            float w = sW[k][tc * 4 + c];
            acc[0][c] += z0 * w;
            acc[1][c] += z1 * w;
        }
    }
    #pragma unroll
    for (int i = 0; i < 2; ++i) {
        int n = node0 + tr * 2 + i;
        if (n < NN) {
            float4 o;
            o.x = acc[i][0]; o.y = acc[i][1]; o.z = acc[i][2]; o.w = acc[i][3];
            out4[n * 16 + tc] = o;
        }
    }
}

// ---------------- one gather of x, three MLPs (params 0/1/2) — round-3 verbatim ----------------

__global__ __launch_bounds__(TPB) void k_aggmlp3(
    const float4* __restrict__ h4,
    const int* __restrict__ row_ptr,
    const int* __restrict__ colv,
    const float* __restrict__ W1a, const float* __restrict__ b1a,
    const float* __restrict__ W2a, const float* __restrict__ b2a,
    const float* __restrict__ W1b, const float* __restrict__ b1b,
    const float* __restrict__ W2b, const float* __restrict__ b2b,
    const float* __restrict__ W1c, const float* __restrict__ b1c,
    const float* __restrict__ W2c, const float* __restrict__ b2c,
    float4* __restrict__ outA, float4* __restrict__ outB, float4* __restrict__ outC)
{
    __shared__ float sW[D][D];          // 16 KB, reloaded per layer
    __shared__ float4 sZ4[TILE][17];    // z = x + agg (preserved)
    __shared__ float4 sH4[TILE][17];    // layer-1 output
    __shared__ float sB[D];

    int tid = threadIdx.x;
    int node0 = blockIdx.x * TILE;

    int wave = tid >> 6, lane = tid & 63;
    int g = lane >> 4, q = lane & 15;

    for (int r = wave; r < TILE; r += (TPB / 64)) {
        int n = node0 + r;
        float4 a = gather_row(h4, row_ptr, colv, (n < NN) ? n : -1, g, q);
        if (g == 0) sZ4[r][q] = a;
    }

    int tr = tid >> 4, tc = tid & 15;
    float* zr0 = (float*)&sZ4[tr * 2 + 0][0];
    float* zr1 = (float*)&sZ4[tr * 2 + 1][0];
    float* hr0 = (float*)&sH4[tr * 2 + 0][0];
    float* hr1 = (float*)&sH4[tr * 2 + 1][0];

    #pragma unroll 1
    for (int m = 0; m < 3; ++m) {
        const float* W1 = (m == 0) ? W1a : (m == 1) ? W1b : W1c;
        const float* B1 = (m == 0) ? b1a : (m == 1) ? b1b : b1c;
        const float* W2 = (m == 0) ? W2a : (m == 1) ? W2b : W2c;
        const float* B2 = (m == 0) ? b2a : (m == 1) ? b2b : b2c;
        float4* out4 = (m == 0) ? outA : (m == 1) ? outB : outC;

        // load W1, b1 (first iteration's sync also covers the gather)
        {
            const float4* w4 = (const float4*)W1;
            float4* s4 = (float4*)sW;
            for (int i = tid; i < D * D / 4; i += TPB) s4[i] = w4[i];
            if (tid < D) sB[tid] = B1[tid];
        }
        __syncthreads();

        float acc[2][4];
        #pragma unroll
        for (int c = 0; c < 4; ++c) { acc[0][c] = sB[tc * 4 + c]; acc[1][c] = sB[tc * 4 + c]; }
        #pragma unroll 16
        for (int k = 0; k < D; ++k) {
            float z0 = zr0[k], z1 = zr1[k];
            #pragma unroll
            for (int c = 0; c < 4; ++c) {
                float w = sW[k][tc * 4 + c];
                acc[0][c] += z0 * w;
                acc[1][c] += z1 * w;
            }
        }
        {
            float4 h0, h1;
            h0.x = fmaxf(acc[0][0], 0.f); h0.y = fmaxf(acc[0][1], 0.f);
            h0.z = fmaxf(acc[0][2], 0.f); h0.w = fmaxf(acc[0][3], 0.f);
            h1.x = fmaxf(acc[1][0], 0.f); h1.y = fmaxf(acc[1][1], 0.f);
            h1.z = fmaxf(acc[1][2], 0.f); h1.w = fmaxf(acc[1][3], 0.f);
            *(float4*)&hr0[tc * 4] = h0;
            *(float4*)&hr1[tc * 4] = h1;
        }
        __syncthreads();

        // load W2, b2
        {
            const float4* w4 = (const float4*)W2;
            float4* s4 = (float4*)sW;
            for (int i = tid; i < D * D / 4; i += TPB) s4[i] = w4[i];
            if (tid < D) sB[tid] = B2[tid];
        }
        __syncthreads();

        #pragma unroll
        for (int c = 0; c < 4; ++c) { acc[0][c] = sB[tc * 4 + c]; acc[1][c] = sB[tc * 4 + c]; }
        #pragma unroll 16
        for (int k = 0; k < D; ++k) {
            float h0 = hr0[k], h1 = hr1[k];
            #pragma unroll
            for (int c = 0; c < 4; ++c) {
                float w = sW[k][tc * 4 + c];
                acc[0][c] += h0 * w;
                acc[1][c] += h1 * w;
            }
        }
        #pragma unroll
        for (int i = 0; i < 2; ++i) {
            int n = node0 + tr * 2 + i;
            if (n < NN) {
                float4 o;
                o.x = acc[i][0]; o.y = acc[i][1]; o.z = acc[i][2]; o.w = acc[i][3];
                out4[n * 16 + tc] = o;
            }
        }
        __syncthreads();   // protect sW/sB before next MLP's load
    }
}

// ---------------- final projection, chunked: out = bo + sum_c Hc @ Wo[c] ----------------
// LDS = 16K(sW) + 17K(sY) = 34 KB -> 4 blocks/CU.

__global__ __launch_bounds__(TPB, 8) void k_final(
    const float4* __restrict__ H0, const float4* __restrict__ H1,
    const float4* __restrict__ H2,
    const float* __restrict__ Wo, const float* __restrict__ bo,
    float4* __restrict__ out4)
{
    __shared__ float sW[D][D];         // one 64x64 chunk of Wo at a time
    __shared__ float4 sY4[TILE][17];   // one 64-feature slice of [H0|H1|H2]
    __shared__ float sB[D];

    int tid = threadIdx.x;
    int node0 = blockIdx.x * TILE;
    int tr = tid >> 4, tc = tid & 15;
    const float* yr0 = (const float*)&sY4[tr * 2 + 0][0];
    const float* yr1 = (const float*)&sY4[tr * 2 + 1][0];

    float accO[2][4];

    #pragma unroll 1
    for (int m = 0; m < 3; ++m) {
        const float4* Hc = (m == 0) ? H0 : (m == 1) ? H1 : H2;
        {
            const float4* w4 = (const float4*)(Wo + m * 64 * D);
            float4* s4 = (float4*)sW;
            for (int i = tid; i < D * D / 4; i += TPB) s4[i] = w4[i];
            if (m == 0 && tid < D) sB[tid] = bo[tid];
        }
        for (int i = tid; i < TILE * 16; i += TPB) {
            int r = i >> 4, qq = i & 15;
            int n = node0 + r;
            sY4[r][qq] = (n < NN) ? Hc[n * 16 + qq] : make_float4(0.f, 0.f, 0.f, 0.f);
        }
        __syncthreads();

        if (m == 0) {
            #pragma unroll
            for (int c = 0; c < 4; ++c) { accO[0][c] = sB[tc * 4 + c]; accO[1][c] = sB[tc * 4 + c]; }
        }
        #pragma unroll 16
        for (int k = 0; k < D; ++k) {
            float z0 = yr0[k], z1 = yr1[k];
            #pragma unroll
            for (int c = 0; c < 4; ++c) {
                float w = sW[k][tc * 4 + c];
                accO[0][c] += z0 * w;
                accO[1][c] += z1 * w;
            }
        }
        __syncthreads();   // before next chunk overwrites sW/sY
    }

    #pragma unroll
    for (int i = 0; i < 2; ++i) {
        int n = node0 + tr * 2 + i;
        if (n < NN) {
            float4 o;
            o.x = accO[i][0]; o.y = accO[i][1]; o.z = accO[i][2]; o.w = accO[i][3];
            out4[n * 16 + tc] = o;
        }
    }
}

// ---------------- launch ----------------

extern "C" void kernel_launch(void* const* d_in, const int* in_sizes, int n_in,
                              void* d_out, int out_size, void* d_ws, size_t ws_size,
                              hipStream_t stream) {
    const float* x    = (const float*)d_in[0];
    const int*   ei   = (const int*)d_in[1];   // [2, NE] int32
    const float* W1_0 = (const float*)d_in[2];
    const float* b1_0 = (const float*)d_in[3];
    const float* W2_0 = (const float*)d_in[4];
    const float* b2_0 = (const float*)d_in[5];
    const float* W1_1 = (const float*)d_in[6];
    const float* b1_1 = (const float*)d_in[7];
    const float* W2_1 = (const float*)d_in[8];
    const float* b2_1 = (const float*)d_in[9];
    const float* W1_2 = (const float*)d_in[10];
    const float* b1_2 = (const float*)d_in[11];
    const float* W2_2 = (const float*)d_in[12];
    const float* b2_2 = (const float*)d_in[13];
    const float* Wo   = (const float*)d_in[14];
    const float* bo   = (const float*)d_in[15];
    float4* out = (float4*)d_out;

    char* ws = (char*)d_ws;
    int* deg     = (int*)(ws + 0);
    int* cursor  = (int*)(ws + 200704);
    int* row_ptr = (int*)(ws + 401408);
    int* colv    = (int*)(ws + 602112);
    int* bsum    = (int*)(ws + 3802112);
    int* boff    = (int*)(ws + 3803136);
    float* fbase = (float*)(ws + 3804160);
    float4* H0  = (float4*)(fbase);
    float4* H1  = (float4*)(fbase + 3200000);
    float4* tB  = (float4*)(fbase + 6400000);   // later reused as H2
    float4* tC2 = (float4*)(fbase + 9600000);
    const float4* x4 = (const float4*)x;

    // CSR build
    hipMemsetAsync(deg, 0, NN * sizeof(int), stream);
    k_count<<<(NE + 255) / 256, 256, 0, stream>>>(ei, deg);
    k_bsum <<<NBLK, 256, 0, stream>>>(deg, bsum);
    k_boff <<<1, 256, 0, stream>>>(bsum, boff, row_ptr);
    k_scan2<<<NBLK, 256, 0, stream>>>(deg, boff, row_ptr, cursor);
    k_fill <<<(NE + 255) / 256, 256, 0, stream>>>(ei, cursor, colv);

    int nb = (NN + TILE - 1) / TILE;  // 782

    // one gather of x, three MLPs: H0 = f0(x), tB = f1(x), out = f2(x)
    k_aggmlp3<<<nb, TPB, 0, stream>>>(x4, row_ptr, colv,
                                      W1_0, b1_0, W2_0, b2_0,
                                      W1_1, b1_1, W2_1, b2_1,
                                      W1_2, b1_2, W2_2, b2_2,
                                      H0, tB, out);

    // hop-2 tail: H1 = f1(tB)
    k_conv<<<nb, TPB, 0, stream>>>((const float4*)tB, row_ptr, colv,
                                   W1_1, b1_1, W2_1, b2_1, H1);

    // hop-3: tC2 = f2(out); H2 (tB reused) = f2(tC2)
    k_conv<<<nb, TPB, 0, stream>>>((const float4*)out, row_ptr, colv,
                                   W1_2, b1_2, W2_2, b2_2, tC2);
    k_conv<<<nb, TPB, 0, stream>>>((const float4*)tC2, row_ptr, colv,
                                   W1_2, b1_2, W2_2, b2_2, tB);

    // final projection
    k_final<<<nb, TPB, 0, stream>>>((const float4*)H0, (const float4*)H1, (const float4*)tB,
                                    Wo, bo, out);
}